// Round 6
// baseline (5619.992 us; speedup 1.0000x reference)
//
#include <hip/hip_runtime.h>
#include <hip/hip_bf16.h>
#include <math.h>

#define SEQ   1024
#define BATCH 256
#define IND   256
#define HID   256
#define NGATE 4

// ws layout:
//   wb    : bf16 [2 parts][4 gates][256 j][256 k], swizzled rows (1 MiB) @ 0
//   hring : bf16 [2][256 b][256 j] LINEAR, LSB = step stamp (2 x 128 KiB) @ 1 MiB
#define WB_BYTES    (2 * NGATE * HID * 256 * 2)
#define HRING_HALF  (BATCH * 512)

typedef float  f32x4  __attribute__((ext_vector_type(4)));
typedef short  bf16x8 __attribute__((ext_vector_type(8)));
typedef unsigned long long u64;

#define LSB_MASK 0x0001000100010001ULL

__device__ __forceinline__ short f2bf(float x) {
    __hip_bfloat16 h = __float2bfloat16(x);
    return *reinterpret_cast<short*>(&h);
}

__device__ __forceinline__ bf16x8 pack8(const float4& a, const float4& b) {
    union { short sh[8]; bf16x8 v; } u;
    u.sh[0] = f2bf(a.x); u.sh[1] = f2bf(a.y); u.sh[2] = f2bf(a.z); u.sh[3] = f2bf(a.w);
    u.sh[4] = f2bf(b.x); u.sh[5] = f2bf(b.y); u.sh[6] = f2bf(b.z); u.sh[7] = f2bf(b.w);
    return u.v;
}

__device__ __forceinline__ void gload_lds16(const void* g, void* l) {
    __builtin_amdgcn_global_load_lds(
        (const __attribute__((address_space(1))) unsigned int*)g,
        (__attribute__((address_space(3))) unsigned int*)l, 16, 0, 0);
}

__device__ __forceinline__ float sigmoid_f(float z) {
    return 1.f / (1.f + __expf(-z));
}
__device__ __forceinline__ float tanh_f(float v) {
    return 2.f / (1.f + __expf(-2.f * v)) - 1.f;
}

// stamp of ring unit freshness: occupant step t carries LSB = (t>>1)&1
__device__ __forceinline__ bool stamp_ok(u64 q0, u64 q1, u64 ee) {
    return ((((q0 ^ ee) | (q1 ^ ee)) & LSB_MASK) == 0ULL);
}

// ---------------- prep kernels ----------------

__global__ __launch_bounds__(256) void prep_w(
    const float* __restrict__ Wf, const float* __restrict__ Wi,
    const float* __restrict__ Wg, const float* __restrict__ Wo,
    unsigned char* __restrict__ wb)
{
    int chunk = blockIdx.x * 256 + threadIdx.x;   // 65536 chunks of 8 floats
    int g  = chunk >> 14;
    int jj = (chunk >> 6) & 255;
    int k0 = (chunk & 63) * 8;
    int p  = k0 >> 8;
    int kk = k0 & 255;
    const float* W = (g == 0) ? Wf : (g == 1) ? Wi : (g == 2) ? Wg : Wo;
    const float* src = W + (size_t)jj * 512 + k0;
    float4 a = *reinterpret_cast<const float4*>(src);
    float4 b = *reinterpret_cast<const float4*>(src + 4);
    size_t dstrow = (size_t)((p * 4 + g) * 256 + jj);
    *reinterpret_cast<bf16x8*>(
        wb + dstrow * 512 + ((kk * 2) ^ ((jj & 7) << 4))) = pack8(a, b);
}

// slot0 <- h0 with LSB=1 (stamp of occupant t=-1); slot1 <- dummy LSB=1
// (expected stamp for its first occupant t=0 is 0, so consumers reject it).
__global__ __launch_bounds__(256) void prep_h0(
    const float* __restrict__ h0, unsigned char* __restrict__ hring)
{
    int chunk = blockIdx.x * 256 + threadIdx.x;   // 8192 chunks of 8
    int b  = chunk >> 5;
    int k0 = (chunk & 31) * 8;
    const float* src = h0 + (size_t)b * HID + k0;
    float4 a = *reinterpret_cast<const float4*>(src);
    float4 c = *reinterpret_cast<const float4*>(src + 4);
    union { short sh[8]; bf16x8 v; } u;
    u.v = pack8(a, c);
    #pragma unroll
    for (int i = 0; i < 8; ++i) u.sh[i] |= 1;     // stamp = 1
    *reinterpret_cast<bf16x8*>(hring + (size_t)b * 512 + k0 * 2) = u.v;
    *reinterpret_cast<bf16x8*>(hring + HRING_HALF + (size_t)b * 512 + k0 * 2) = u.v;
}

// ---------------- persistent sequence kernel ----------------
// 64 blocks x 256 threads; blk -> B = blk&3 (64 b-rows), J = blk>>2 (16 j).
// W fragments in VGPRs/AGPRs for the whole sequence. Per step:
//   [issue stamped h(s-1) loads] [phase A: x-part MFMA] [stamp check+retry]
//   [phase B: h-part MFMA] [epilogue -> LDS stage] [bar]
//   [coalesced stamped h store + out store] [x(s+1) prefetch]
// No flags, no ACK drains: freshness is policed by the in-data stamps.
__global__ __launch_bounds__(256, 1) void lstm_seq(
    const float* __restrict__ x,  const float* __restrict__ c0,
    const float* __restrict__ bf_, const float* __restrict__ bi_,
    const float* __restrict__ bg_, const float* __restrict__ bo_,
    const unsigned char* __restrict__ wb, unsigned char* __restrict__ hring,
    float* __restrict__ out, float* __restrict__ hx, float* __restrict__ cxg)
{
    extern __shared__ __align__(16) unsigned char smem[];   // 64 KiB

    const int tid  = threadIdx.x;
    const int lane = tid & 63;
    const int w    = tid >> 6;
    const int blk  = blockIdx.x;
    const int B    = blk & 3;
    const int J    = blk >> 2;
    const int j0   = J * 16;
    const int b0   = B * 64;

    const int lrow = lane & 15;
    const int hi   = lane >> 4;
    const int j    = j0 + lrow;
    const int hrow = b0 + w * 16 + lrow;     // this lane's A-fragment row

    // ---- stage W tile to LDS once (64 x 1 KiB issues)
    #pragma unroll
    for (int i = 0; i < 16; ++i) {
        int idx = w * 16 + i;
        gload_lds16(wb + ((size_t)((idx >> 3) * 256 + j0 + (idx & 7) * 2)) * 512
                       + lane * 16,
                    smem + idx * 1024);
    }
    const float biasF = bf_[j], biasI = bi_[j], biasG = bg_[j], biasO = bo_[j];
    float cst[4];
    #pragma unroll
    for (int r = 0; r < 4; ++r)
        cst[r] = c0[(b0 + w * 16 + hi * 4 + r) * HID + j];
    __syncthreads();

    // ---- read all W fragments into registers: wf[part][kc][gate]
    const int bswz = (lrow & 7) << 4;
    bf16x8 wf[2][8][4];
    #pragma unroll
    for (int p = 0; p < 2; ++p) {
        #pragma unroll
        for (int kc = 0; kc < 8; ++kc) {
            int wbyte = (kc * 64 + hi * 16) ^ bswz;
            #pragma unroll
            for (int g = 0; g < 4; ++g)
                wf[p][kc][g] = *reinterpret_cast<const bf16x8*>(
                    smem + p * 32768 + g * 8192 + lrow * 512 + wbyte);
        }
    }
    __syncthreads();   // frag reads done -> smem reusable as store stage

    unsigned char* hstage = smem;           // [64 local b][16 j] bf16 = 2 KiB
    unsigned char* ostage = smem + 2048;    // [64 local b][16 j] f32  = 4 KiB

    // ---- prologue: x(0) fragment loads
    float4 xn0[8], xn1[8];
    {
        const float* xr = x + (size_t)hrow * IND;
        #pragma unroll
        for (int kc = 0; kc < 8; ++kc) {
            const float* p = xr + kc * 32 + hi * 8;
            xn0[kc] = *reinterpret_cast<const float4*>(p);
            xn1[kc] = *reinterpret_cast<const float4*>(p + 4);
        }
    }

    for (int s = 0; s < SEQ; ++s) {
        // expected stamp of occupant t = s-1:  ((s+3)>>1)&1  (== ((s-1)>>1)&1)
        const u64 ee = (((unsigned)(s + 3) >> 1) & 1) ? LSB_MASK : 0ULL;
        const unsigned char* hsrc =
            hring + (size_t)(s & 1) * HRING_HALF + (size_t)hrow * 512;

        // ---- issue stamped h loads (latency hides under phase A)
        u64 hq0[8], hq1[8];
        #pragma unroll
        for (int kc = 0; kc < 8; ++kc) {
            const u64* p = reinterpret_cast<const u64*>(hsrc + kc * 64 + hi * 16);
            hq0[kc] = __hip_atomic_load(p,     __ATOMIC_RELAXED, __HIP_MEMORY_SCOPE_AGENT);
            hq1[kc] = __hip_atomic_load(p + 1, __ATOMIC_RELAXED, __HIP_MEMORY_SCOPE_AGENT);
        }
        __builtin_amdgcn_sched_barrier(0);

        // ---- phase A: x-part MFMA, operands in registers
        f32x4 aF = {0.f, 0.f, 0.f, 0.f};
        f32x4 aI = {0.f, 0.f, 0.f, 0.f};
        f32x4 aG = {0.f, 0.f, 0.f, 0.f};
        f32x4 aO = {0.f, 0.f, 0.f, 0.f};
        #pragma unroll
        for (int kc = 0; kc < 8; ++kc) {
            bf16x8 af = pack8(xn0[kc], xn1[kc]);
            aF = __builtin_amdgcn_mfma_f32_16x16x32_bf16(af, wf[0][kc][0], aF, 0, 0, 0);
            aI = __builtin_amdgcn_mfma_f32_16x16x32_bf16(af, wf[0][kc][1], aI, 0, 0, 0);
            aG = __builtin_amdgcn_mfma_f32_16x16x32_bf16(af, wf[0][kc][2], aG, 0, 0, 0);
            aO = __builtin_amdgcn_mfma_f32_16x16x32_bf16(af, wf[0][kc][3], aO, 0, 0, 0);
        }

        // ---- stamp check + retry (per-lane; converges when all units fresh)
        unsigned pend = 0;
        #pragma unroll
        for (int kc = 0; kc < 8; ++kc)
            if (!stamp_ok(hq0[kc], hq1[kc], ee)) pend |= (1u << kc);
        while (pend) {
            __builtin_amdgcn_s_sleep(2);
            #pragma unroll
            for (int kc = 0; kc < 8; ++kc) {
                if (pend & (1u << kc)) {
                    const u64* p = reinterpret_cast<const u64*>(hsrc + kc * 64 + hi * 16);
                    hq0[kc] = __hip_atomic_load(p,     __ATOMIC_RELAXED, __HIP_MEMORY_SCOPE_AGENT);
                    hq1[kc] = __hip_atomic_load(p + 1, __ATOMIC_RELAXED, __HIP_MEMORY_SCOPE_AGENT);
                    if (stamp_ok(hq0[kc], hq1[kc], ee)) pend &= ~(1u << kc);
                }
            }
        }

        // ---- phase B: h-part MFMA
        #pragma unroll
        for (int kc = 0; kc < 8; ++kc) {
            union { u64 q[2]; bf16x8 v; } u;
            u.q[0] = hq0[kc]; u.q[1] = hq1[kc];
            aF = __builtin_amdgcn_mfma_f32_16x16x32_bf16(u.v, wf[1][kc][0], aF, 0, 0, 0);
            aI = __builtin_amdgcn_mfma_f32_16x16x32_bf16(u.v, wf[1][kc][1], aI, 0, 0, 0);
            aG = __builtin_amdgcn_mfma_f32_16x16x32_bf16(u.v, wf[1][kc][2], aG, 0, 0, 0);
            aO = __builtin_amdgcn_mfma_f32_16x16x32_bf16(u.v, wf[1][kc][3], aO, 0, 0, 0);
        }

        // ---- epilogue: gates, c in regs, stage stamped h(bf16) + out(f32)
        const unsigned short st = (unsigned short)((s >> 1) & 1);
        float* outp = out + (size_t)s * (BATCH * HID);
        unsigned char* hdst = hring + (size_t)((s + 1) & 1) * HRING_HALF;
        #pragma unroll
        for (int r = 0; r < 4; ++r) {
            int rl = w * 16 + hi * 4 + r;    // local b row 0..63
            float fg = sigmoid_f(aF[r] + biasF);
            float ig = sigmoid_f(aI[r] + biasI);
            float gg = tanh_f(aG[r] + biasG);
            float og = sigmoid_f(aO[r] + biasO);
            cst[r]  = fg * cst[r] + ig * gg;
            float h = og * tanh_f(cst[r]);
            unsigned short hb =
                (unsigned short)(((unsigned short)f2bf(h) & 0xFFFEu) | st);
            *reinterpret_cast<unsigned short*>(hstage + rl * 32 + lrow * 2) = hb;
            *reinterpret_cast<float*>(ostage + rl * 64 + lrow * 4) = h;
            if (s == SEQ - 1) {
                int gi = (b0 + rl) * HID + j;
                hx[gi] = h; cxg[gi] = cst[r];
            }
        }
        __syncthreads();   // stage visible to the coalescing threads

        // ---- coalesced stores: 8 B stamped h (device-coherent) + 16 B out
        {
            u64    hv = *reinterpret_cast<const u64*>(hstage + tid * 8);
            float4 ov = *reinterpret_cast<const float4*>(ostage + tid * 16);
            u64* hp = reinterpret_cast<u64*>(
                hdst + (size_t)(b0 + (tid >> 2)) * 512 + j0 * 2 + (tid & 3) * 8);
            __hip_atomic_store(hp, hv, __ATOMIC_RELAXED, __HIP_MEMORY_SCOPE_AGENT);
            *reinterpret_cast<float4*>(
                outp + (size_t)(b0 + (tid >> 2)) * HID + j0 + (tid & 3) * 4) = ov;
        }

        // ---- x(s+1) prefetch (no drains; stamps police everything)
        if (s + 1 < SEQ) {
            const float* xr = x + ((size_t)(s + 1) * BATCH + hrow) * IND;
            #pragma unroll
            for (int kc = 0; kc < 8; ++kc) {
                const float* p = xr + kc * 32 + hi * 8;
                xn0[kc] = *reinterpret_cast<const float4*>(p);
                xn1[kc] = *reinterpret_cast<const float4*>(p + 4);
            }
        }
    }
}

extern "C" void kernel_launch(void* const* d_in, const int* in_sizes, int n_in,
                              void* d_out, int out_size, void* d_ws, size_t ws_size,
                              hipStream_t stream) {
    const float* x  = (const float*)d_in[0];
    const float* h0 = (const float*)d_in[1];
    const float* c0 = (const float*)d_in[2];
    const float* Wf = (const float*)d_in[3];
    const float* bf = (const float*)d_in[4];
    const float* Wi = (const float*)d_in[5];
    const float* bi = (const float*)d_in[6];
    const float* Wg = (const float*)d_in[7];
    const float* bg = (const float*)d_in[8];
    const float* Wo = (const float*)d_in[9];
    const float* bo = (const float*)d_in[10];

    float* out = (float*)d_out;
    float* hx  = out + (size_t)SEQ * BATCH * HID;
    float* cx  = hx + BATCH * HID;

    unsigned char* wb = (unsigned char*)d_ws;
    unsigned char* hb = wb + WB_BYTES;

    prep_w<<<256, 256, 0, stream>>>(Wf, Wi, Wg, Wo, wb);
    prep_h0<<<32, 256, 0, stream>>>(h0, hb);
    lstm_seq<<<64, 256, 65536, stream>>>(x, c0, bf, bi, bg, bo,
                                         wb, hb, out, hx, cx);
}

// Round 7
// 3708.233 us; speedup vs baseline: 1.5155x; 1.5155x over previous
//
#include <hip/hip_runtime.h>
#include <hip/hip_bf16.h>
#include <math.h>

#define SEQ   1024
#define BATCH 256
#define IND   256
#define HID   256
#define NGATE 4

// ws layout:
//   wb : bf16 [2 parts][4 gates][256 j][256 k], swizzled rows (1 MiB) @ 0
//   hr : bf16 regions [2 slots][16 g][16 J][16 b][16 j], LSB-stamped
//        (512 B per region, single writer each; 256 KiB total)  @ 1 MiB
#define WB_BYTES   (2 * NGATE * HID * 256 * 2)
#define REG_BYTES  512

typedef float  f32x4  __attribute__((ext_vector_type(4)));
typedef short  bf16x8 __attribute__((ext_vector_type(8)));
typedef unsigned long long u64;

#define LSB_MASK 0x0001000100010001ULL

__device__ __forceinline__ short f2bf(float x) {
    __hip_bfloat16 h = __float2bfloat16(x);
    return *reinterpret_cast<short*>(&h);
}

__device__ __forceinline__ bf16x8 pack8(const float4& a, const float4& b) {
    union { short sh[8]; bf16x8 v; } u;
    u.sh[0] = f2bf(a.x); u.sh[1] = f2bf(a.y); u.sh[2] = f2bf(a.z); u.sh[3] = f2bf(a.w);
    u.sh[4] = f2bf(b.x); u.sh[5] = f2bf(b.y); u.sh[6] = f2bf(b.z); u.sh[7] = f2bf(b.w);
    return u.v;
}

__device__ __forceinline__ void gload_lds16(const void* g, void* l) {
    __builtin_amdgcn_global_load_lds(
        (const __attribute__((address_space(1))) unsigned int*)g,
        (__attribute__((address_space(3))) unsigned int*)l, 16, 0, 0);
}

__device__ __forceinline__ float sigmoid_f(float z) {
    return 1.f / (1.f + __expf(-z));
}
__device__ __forceinline__ float tanh_f(float v) {
    return 2.f / (1.f + __expf(-2.f * v)) - 1.f;
}

__device__ __forceinline__ bool stamp_ok(u64 q0, u64 q1, u64 ee) {
    return ((((q0 ^ ee) | (q1 ^ ee)) & LSB_MASK) == 0ULL);
}

// ---------------- prep kernels ----------------

__global__ __launch_bounds__(256) void prep_w(
    const float* __restrict__ Wf, const float* __restrict__ Wi,
    const float* __restrict__ Wg, const float* __restrict__ Wo,
    unsigned char* __restrict__ wb)
{
    int chunk = blockIdx.x * 256 + threadIdx.x;   // 65536 chunks of 8 floats
    int g  = chunk >> 14;
    int jj = (chunk >> 6) & 255;
    int k0 = (chunk & 63) * 8;
    int p  = k0 >> 8;
    int kk = k0 & 255;
    const float* W = (g == 0) ? Wf : (g == 1) ? Wi : (g == 2) ? Wg : Wo;
    const float* src = W + (size_t)jj * 512 + k0;
    float4 a = *reinterpret_cast<const float4*>(src);
    float4 b = *reinterpret_cast<const float4*>(src + 4);
    size_t dstrow = (size_t)((p * 4 + g) * 256 + jj);
    *reinterpret_cast<bf16x8*>(
        wb + dstrow * 512 + ((kk * 2) ^ ((jj & 7) << 4))) = pack8(a, b);
}

// Seed h regions: slot0 = h0 (stamp 1 = occupant t=-1); slot1 = dummy stamp 1
// (its first expected stamp is 0, so consumers reject until overwritten).
__global__ __launch_bounds__(256) void prep_h0(
    const float* __restrict__ h0, unsigned char* __restrict__ hr)
{
    int idx  = blockIdx.x * 256 + threadIdx.x;    // 32768 chunks of 8 B
    int slot = idx >> 14;
    int g    = (idx >> 10) & 15;
    int J    = (idx >> 6) & 15;
    int c    = idx & 63;
    int br   = c >> 2;
    int j4   = (c & 3) * 4;
    const float* src = h0 + (size_t)(g * 16 + br) * HID + J * 16 + j4;
    unsigned short v[4];
    #pragma unroll
    for (int i = 0; i < 4; ++i)
        v[i] = (unsigned short)((unsigned short)f2bf(src[i]) | 1u);
    u64 q = (u64)v[0] | ((u64)v[1] << 16) | ((u64)v[2] << 32) | ((u64)v[3] << 48);
    *reinterpret_cast<u64*>(
        hr + (size_t)((slot * 16 + g) * 16 + J) * REG_BYTES + c * 8) = q;
}

// ---------------- persistent sequence kernel ----------------
// 256 blocks x 64 threads (one wave per CU). blk -> g = blk>>4 (16 b-rows),
// J = blk&15 (16 j). W fragments resident in the unified RF all sequence.
// Steady loop has ZERO LDS ops and ZERO barriers. Per step:
//   [issue h(s-1) region loads] [phase A: pure x-MFMA from packed regs]
//   [pack x(s+1); issue x(s+2)] [stamp check+retry] [phase B: h-MFMA]
//   [epilogue: gates, c-regs, 2B stamped h stores (private region), out]
__global__ __launch_bounds__(64, 1) void lstm_seq(
    const float* __restrict__ x,  const float* __restrict__ c0,
    const float* __restrict__ bf_, const float* __restrict__ bi_,
    const float* __restrict__ bg_, const float* __restrict__ bo_,
    const unsigned char* __restrict__ wb, unsigned char* __restrict__ hr,
    float* __restrict__ out, float* __restrict__ hx, float* __restrict__ cxg)
{
    extern __shared__ __align__(16) unsigned char smem[];   // 64 KiB, init only

    const int lane = threadIdx.x & 63;
    const int blk  = blockIdx.x;
    const int g_   = blk >> 4;          // b-group 0..15
    const int J    = blk & 15;          // j-tile  0..15
    const int j0   = J * 16;
    const int b0   = g_ * 16;

    const int lrow = lane & 15;
    const int hi   = lane >> 4;
    const int j    = j0 + lrow;

    // ---- stage W tile (64 KiB) into LDS once
    #pragma unroll
    for (int i = 0; i < 64; ++i) {
        gload_lds16(wb + ((size_t)((i >> 3) * 256 + j0 + (i & 7) * 2)) * 512
                       + lane * 16,
                    smem + i * 1024);
    }
    const float biasF = bf_[j], biasI = bi_[j], biasG = bg_[j], biasO = bo_[j];
    float cst[4];
    #pragma unroll
    for (int r = 0; r < 4; ++r)
        cst[r] = c0[(b0 + hi * 4 + r) * HID + j];
    __syncthreads();    // drains gload_lds (vmcnt)

    // ---- read all W fragments into the register file: wf[part][kc][gate]
    const int bswz = (lrow & 7) << 4;
    bf16x8 wf[2][8][4];
    #pragma unroll
    for (int p = 0; p < 2; ++p) {
        #pragma unroll
        for (int kc = 0; kc < 8; ++kc) {
            int wbyte = (kc * 64 + hi * 16) ^ bswz;
            #pragma unroll
            for (int gg = 0; gg < 4; ++gg)
                wf[p][kc][gg] = *reinterpret_cast<const bf16x8*>(
                    smem + p * 32768 + gg * 8192 + lrow * 512 + wbyte);
        }
    }
    // LDS unused from here on.

    // ---- x pipeline: xpk = packed x(s); xt = in-flight x(s+1)
    float4 xt0[8], xt1[8];
    bf16x8 xpk[8];
    {
        const float* xr = x + (size_t)(b0 + lrow) * IND;
        #pragma unroll
        for (int kc = 0; kc < 8; ++kc) {
            const float* p = xr + kc * 32 + hi * 8;
            xt0[kc] = *reinterpret_cast<const float4*>(p);
            xt1[kc] = *reinterpret_cast<const float4*>(p + 4);
        }
        #pragma unroll
        for (int kc = 0; kc < 8; ++kc) xpk[kc] = pack8(xt0[kc], xt1[kc]);
        const float* xr1 = x + ((size_t)BATCH + b0 + lrow) * IND;
        #pragma unroll
        for (int kc = 0; kc < 8; ++kc) {
            const float* p = xr1 + kc * 32 + hi * 8;
            xt0[kc] = *reinterpret_cast<const float4*>(p);
            xt1[kc] = *reinterpret_cast<const float4*>(p + 4);
        }
    }

    // consumer region base for my b-group (16 regions x 512 B, contiguous)
    unsigned char* regc[2] = {
        hr + (size_t)((0 * 16 + g_) * 16) * REG_BYTES,
        hr + (size_t)((1 * 16 + g_) * 16) * REG_BYTES };
    // producer region (single writer: this block)
    unsigned char* regp[2] = {
        hr + (size_t)((0 * 16 + g_) * 16 + J) * REG_BYTES,
        hr + (size_t)((1 * 16 + g_) * 16 + J) * REG_BYTES };

    for (int s = 0; s < SEQ; ++s) {
        const u64 ee = (((unsigned)(s + 3) >> 1) & 1) ? LSB_MASK : 0ULL;
        const unsigned char* hsrc = regc[s & 1];

        // ---- issue h(s-1) loads: unit kc -> region 2kc+(hi>>1)
        u64 hq0[8], hq1[8];
        #pragma unroll
        for (int kc = 0; kc < 8; ++kc) {
            const u64* p = reinterpret_cast<const u64*>(
                hsrc + (2 * kc + (hi >> 1)) * REG_BYTES + lrow * 32 + (hi & 1) * 16);
            hq0[kc] = __hip_atomic_load(p,     __ATOMIC_RELAXED, __HIP_MEMORY_SCOPE_AGENT);
            hq1[kc] = __hip_atomic_load(p + 1, __ATOMIC_RELAXED, __HIP_MEMORY_SCOPE_AGENT);
        }
        __builtin_amdgcn_sched_barrier(0);

        // ---- phase A: pure MFMA (x part)
        f32x4 aF = {0.f, 0.f, 0.f, 0.f};
        f32x4 aI = {0.f, 0.f, 0.f, 0.f};
        f32x4 aG = {0.f, 0.f, 0.f, 0.f};
        f32x4 aO = {0.f, 0.f, 0.f, 0.f};
        #pragma unroll
        for (int kc = 0; kc < 8; ++kc) {
            aF = __builtin_amdgcn_mfma_f32_16x16x32_bf16(xpk[kc], wf[0][kc][0], aF, 0, 0, 0);
            aI = __builtin_amdgcn_mfma_f32_16x16x32_bf16(xpk[kc], wf[0][kc][1], aI, 0, 0, 0);
            aG = __builtin_amdgcn_mfma_f32_16x16x32_bf16(xpk[kc], wf[0][kc][2], aG, 0, 0, 0);
            aO = __builtin_amdgcn_mfma_f32_16x16x32_bf16(xpk[kc], wf[0][kc][3], aO, 0, 0, 0);
        }

        // ---- pack x(s+1) -> xpk; issue x(s+2) -> xt  (off the h critical path)
        #pragma unroll
        for (int kc = 0; kc < 8; ++kc) xpk[kc] = pack8(xt0[kc], xt1[kc]);
        if (s + 2 < SEQ) {
            const float* xr = x + ((size_t)(s + 2) * BATCH + b0 + lrow) * IND;
            #pragma unroll
            for (int kc = 0; kc < 8; ++kc) {
                const float* p = xr + kc * 32 + hi * 8;
                xt0[kc] = *reinterpret_cast<const float4*>(p);
                xt1[kc] = *reinterpret_cast<const float4*>(p + 4);
            }
        }
        __builtin_amdgcn_sched_barrier(0);

        // ---- stamp check + retry
        unsigned pend = 0;
        #pragma unroll
        for (int kc = 0; kc < 8; ++kc)
            if (!stamp_ok(hq0[kc], hq1[kc], ee)) pend |= (1u << kc);
        while (pend) {
            __builtin_amdgcn_s_sleep(1);
            #pragma unroll
            for (int kc = 0; kc < 8; ++kc) {
                if (pend & (1u << kc)) {
                    const u64* p = reinterpret_cast<const u64*>(
                        hsrc + (2 * kc + (hi >> 1)) * REG_BYTES + lrow * 32 + (hi & 1) * 16);
                    hq0[kc] = __hip_atomic_load(p,     __ATOMIC_RELAXED, __HIP_MEMORY_SCOPE_AGENT);
                    hq1[kc] = __hip_atomic_load(p + 1, __ATOMIC_RELAXED, __HIP_MEMORY_SCOPE_AGENT);
                    if (stamp_ok(hq0[kc], hq1[kc], ee)) pend &= ~(1u << kc);
                }
            }
        }

        // ---- phase B: h-part MFMA
        #pragma unroll
        for (int kc = 0; kc < 8; ++kc) {
            union { u64 q[2]; bf16x8 v; } u;
            u.q[0] = hq0[kc]; u.q[1] = hq1[kc];
            aF = __builtin_amdgcn_mfma_f32_16x16x32_bf16(u.v, wf[1][kc][0], aF, 0, 0, 0);
            aI = __builtin_amdgcn_mfma_f32_16x16x32_bf16(u.v, wf[1][kc][1], aI, 0, 0, 0);
            aG = __builtin_amdgcn_mfma_f32_16x16x32_bf16(u.v, wf[1][kc][2], aG, 0, 0, 0);
            aO = __builtin_amdgcn_mfma_f32_16x16x32_bf16(u.v, wf[1][kc][3], aO, 0, 0, 0);
        }

        // ---- epilogue: gates, c-update, stamped 2B h stores + out stores
        const unsigned short st = (unsigned short)((s >> 1) & 1);
        float* outp = out + (size_t)s * (BATCH * HID);
        unsigned char* hdst = regp[(s + 1) & 1];
        #pragma unroll
        for (int r = 0; r < 4; ++r) {
            int bl  = hi * 4 + r;            // local b row 0..15
            float fg = sigmoid_f(aF[r] + biasF);
            float ig = sigmoid_f(aI[r] + biasI);
            float gg = tanh_f(aG[r] + biasG);
            float og = sigmoid_f(aO[r] + biasO);
            cst[r]  = fg * cst[r] + ig * gg;
            float h = og * tanh_f(cst[r]);
            unsigned short hb =
                (unsigned short)(((unsigned short)f2bf(h) & 0xFFFEu) | st);
            __hip_atomic_store(
                reinterpret_cast<unsigned short*>(hdst + bl * 32 + lrow * 2),
                hb, __ATOMIC_RELAXED, __HIP_MEMORY_SCOPE_AGENT);
            outp[(size_t)(b0 + bl) * HID + j] = h;
            if (s == SEQ - 1) {
                int gi = (b0 + bl) * HID + j;
                hx[gi] = h; cxg[gi] = cst[r];
            }
        }
    }
}

extern "C" void kernel_launch(void* const* d_in, const int* in_sizes, int n_in,
                              void* d_out, int out_size, void* d_ws, size_t ws_size,
                              hipStream_t stream) {
    const float* x  = (const float*)d_in[0];
    const float* h0 = (const float*)d_in[1];
    const float* c0 = (const float*)d_in[2];
    const float* Wf = (const float*)d_in[3];
    const float* bf = (const float*)d_in[4];
    const float* Wi = (const float*)d_in[5];
    const float* bi = (const float*)d_in[6];
    const float* Wg = (const float*)d_in[7];
    const float* bg = (const float*)d_in[8];
    const float* Wo = (const float*)d_in[9];
    const float* bo = (const float*)d_in[10];

    float* out = (float*)d_out;
    float* hx  = out + (size_t)SEQ * BATCH * HID;
    float* cx  = hx + BATCH * HID;

    unsigned char* wb = (unsigned char*)d_ws;
    unsigned char* hr = wb + WB_BYTES;

    prep_w<<<256, 256, 0, stream>>>(Wf, Wi, Wg, Wo, wb);
    prep_h0<<<128, 256, 0, stream>>>(h0, hr);
    lstm_seq<<<256, 64, 65536, stream>>>(x, c0, bf, bi, bg, bo,
                                         wb, hr, out, hx, cx);
}